// Round 16
// baseline (1100.587 us; speedup 1.0000x reference)
//
#include <hip/hip_runtime.h>
#include <math.h>

#define HN 512   // hidden states
#define HM 4096  // emission symbols
#define HB 64    // batch
#define HT 512   // max seq len

// ---- 4-bit dot path (encoding must match between prep + fwd) ----
#if __has_builtin(__builtin_amdgcn_udot8)
  #define ENC_BIASED 0
  __device__ __forceinline__ int dot8q(unsigned int a, unsigned int b, int c){
    return (int)__builtin_amdgcn_udot8(a, b, (unsigned int)c, false);
  }
#elif __has_builtin(__builtin_amdgcn_sdot8)
  #define ENC_BIASED 1
  __device__ __forceinline__ int dot8q(unsigned int a, unsigned int b, int c){
    return __builtin_amdgcn_sdot8((int)a, (int)b, c, false);
  }
#else
  #define ENC_BIASED 0
  __device__ __forceinline__ int dot4u8f(unsigned int a, unsigned int b, int c){
#if __has_builtin(__builtin_amdgcn_sdot4)
    return __builtin_amdgcn_sdot4((int)a, (int)b, c, false);
#else
    c += (int)(a & 0xffu)       * (int)(b & 0xffu);
    c += (int)((a>>8) & 0xffu)  * (int)((b>>8) & 0xffu);
    c += (int)((a>>16) & 0xffu) * (int)((b>>16) & 0xffu);
    c += (int)(a>>24)           * (int)(b>>24);
    return c;
#endif
  }
  __device__ __forceinline__ int dot8q(unsigned int a, unsigned int b, int c){
    unsigned int al = a & 0x0F0F0F0Fu, ah = (a>>4) & 0x0F0F0F0Fu;
    unsigned int bl = b & 0x0F0F0F0Fu, bh = (b>>4) & 0x0F0F0F0Fu;
    c = dot4u8f(al, bl, c);
    return dot4u8f(ah, bh, c);
  }
#endif

#if __has_builtin(__builtin_amdgcn_readlane)
  __device__ __forceinline__ unsigned rdlaneu(unsigned v, int l){
    return (unsigned)__builtin_amdgcn_readlane((int)v, l);
  }
  __device__ __forceinline__ float rdlanef(float v, int l){
    return __int_as_float(__builtin_amdgcn_readlane(__float_as_int(v), l));
  }
#else
  __device__ __forceinline__ unsigned rdlaneu(unsigned v, int l){ return (unsigned)__shfl((int)v, l, 64); }
  __device__ __forceinline__ float rdlanef(float v, int l){ return __shfl(v, l, 64); }
#endif

__device__ __forceinline__ float rcpf(float x){
#if __has_builtin(__builtin_amdgcn_rcpf)
  return __builtin_amdgcn_rcpf(x);
#else
  return 1.0f / x;
#endif
}

__device__ __forceinline__ float wsum(float v){
  #pragma unroll
  for(int o=32;o>0;o>>=1) v += __shfl_xor(v,o,64);
  return v;
}
__device__ __forceinline__ float wmax(float v){
  #pragma unroll
  for(int o=32;o>0;o>>=1) v = fmaxf(v,__shfl_xor(v,o,64));
  return v;
}

__device__ __forceinline__ float blockSum512(float v, float* red, float* bc){
  v = wsum(v);
  if((threadIdx.x & 63)==0) red[threadIdx.x>>6] = v;
  __syncthreads();
  if(threadIdx.x < 64){
    float s = (threadIdx.x<8)? red[threadIdx.x] : 0.0f;
    #pragma unroll
    for(int o=4;o>0;o>>=1) s += __shfl_xor(s,o,64);
    if(threadIdx.x==0) *bc = s;
  }
  __syncthreads();
  return *bc;
}
__device__ __forceinline__ float blockMax512(float v, float* red, float* bc){
  v = wmax(v);
  if((threadIdx.x & 63)==0) red[threadIdx.x>>6] = v;
  __syncthreads();
  if(threadIdx.x < 64){
    float s = (threadIdx.x<8)? red[threadIdx.x] : -INFINITY;
    #pragma unroll
    for(int o=4;o>0;o>>=1) s = fmaxf(s, __shfl_xor(s,o,64));
    if(threadIdx.x==0) *bc = s;
  }
  __syncthreads();
  return *bc;
}

__device__ __forceinline__ unsigned short f2bf(float f){
  unsigned int u = __float_as_uint(f);
  unsigned int r = (u + 0x7fffu + ((u>>16)&1u)) >> 16;  // RNE
  return (unsigned short)r;
}
__device__ __forceinline__ float bf2f(unsigned int w){ return __uint_as_float(w<<16); }

// ---------------- prep kernels ----------------

__global__ __launch_bounds__(512) void k_em_lse(const float* __restrict__ em, float* __restrict__ em_lse){
  __shared__ float red[8]; __shared__ float bc;
  int r = blockIdx.x;
  const float* row = em + (size_t)r*HM;
  float mx = -INFINITY;
  for(int i=threadIdx.x;i<HM;i+=512) mx = fmaxf(mx, row[i]);
  mx = blockMax512(mx, red, &bc);
  float s = 0.f;
  for(int i=threadIdx.x;i<HM;i+=512) s += expf(row[i]-mx);
  s = blockSum512(s, red, &bc);
  if(threadIdx.x==0) em_lse[r] = mx + logf(s);
}

__global__ __launch_bounds__(512) void k_pri(const float* __restrict__ pri, float* __restrict__ P, float* __restrict__ pric){
  __shared__ float red[8]; __shared__ float bc;
  int j = threadIdx.x;
  float v = pri[j];
  float mx = blockMax512(v, red, &bc);
  float w = expf(v-mx);
  float s = blockSum512(w, red, &bc);
  P[j] = w;
  if(j==0) *pric = -logf(s);
}

// emT[m][j] = bf16( exp(log_em[j][m]) ), LDS-tiled transpose
__global__ __launch_bounds__(256) void k_em_tab(const float* __restrict__ em, const float* __restrict__ em_lse,
                                                unsigned short* __restrict__ emT){
  __shared__ unsigned short tile[64][66];
  __shared__ float lsl[64];
  int m0 = blockIdx.x*64, j0 = blockIdx.y*64;
  int tx = threadIdx.x & 63, ty = threadIdx.x >> 6;
  if(threadIdx.x < 64) lsl[threadIdx.x] = em_lse[j0 + threadIdx.x];
  __syncthreads();
  #pragma unroll
  for(int r=0;r<16;r++){
    int jl = ty*16 + r;
    float v = em[(size_t)(j0+jl)*HM + m0 + tx];
    tile[jl][tx] = f2bf(expf(v - lsl[jl]));
  }
  __syncthreads();
  #pragma unroll
  for(int r=0;r<16;r++){
    int ml = ty*16 + r;
    emT[(size_t)(m0+ml)*HN + j0 + tx] = tile[tx][ml];
  }
}

// column stats of transition col-softmax
__global__ __launch_bounds__(512) void k_trcol(const float* __restrict__ tr,
                                               float* __restrict__ cmax, float* __restrict__ csum){
  __shared__ float red[8]; __shared__ float bc;
  int k = blockIdx.x, j = threadIdx.x;
  float v = tr[(size_t)j*HN + k];
  float mx = blockMax512(v, red, &bc);
  float s  = blockSum512(expf(v-mx), red, &bc);
  if(j==0){ cmax[k] = mx; csum[k] = s; }
}

// row pass: Tr[j,k] -> u4 q = round(Tr*15/rowmax). Byte at j*256 + (k>>5)*16 +
// ((k&31)>>1): lo = even k, hi = k+1 (matches alpha packing).
// rscale[j]=rm/15; rbar[j]=rowsum residual; tsumq[j][w] = per-64k-slice q sum.
__global__ __launch_bounds__(512) void k_trrow(const float* __restrict__ tr,
                                               const float* __restrict__ cmax, const float* __restrict__ csum,
                                               unsigned char* __restrict__ TQ4,
                                               float* __restrict__ rscale, float* __restrict__ rbar,
                                               unsigned short* __restrict__ tsumq){
  __shared__ float red[8]; __shared__ float bc;
  int j = blockIdx.x, k = threadIdx.x;
  float v = expf(tr[(size_t)j*HN + k] - cmax[k]) / csum[k];
  float rm = blockMax512(v, red, &bc);
  int q = __float2int_rn(v * (15.0f/rm));          // 0..15
  float rs = blockSum512(v, red, &bc);             // true row sum
  float qs = blockSum512((float)q, red, &bc);      // total q sum
  float wq = wsum((float)q);                       // per-64k-slice q sum
  int qn = __shfl_down(q, 1, 64);
  if((k & 1)==0){
#if ENC_BIASED
    unsigned char by = (unsigned char)(((q-8)&0xF) | (((qn-8)&0xF)<<4));
#else
    unsigned char by = (unsigned char)((q&0xF) | ((qn&0xF)<<4));
#endif
    TQ4[(size_t)j*256 + ((k>>5)<<4) + ((k&31)>>1)] = by;
  }
  if((k&63)==0) tsumq[j*8 + (k>>6)] = (unsigned short)(int)wq;
  if(k==0){
    rscale[j] = rm * (1.0f/15.0f);
    rbar[j]   = rs - (rm * (1.0f/15.0f)) * qs;
  }
}

// ---------------- forward recurrence ----------------
// 32 blocks (2 batches each), 512 threads = 8 waves; thread = state j.
// Tr row (256 B u4 = 64 dwords) in REGISTERS, filled with SCALAR dword loads —
// r7-proven resident pattern (VGPR 116). uint4-cast fills (r8/r9/r13/r15) always
// produced an unsplittable alloca -> scratch spill (VGPR 36-56). Pin after fill.
// alpha planes + stats via ONE b32 lane-gather per wave + v_readlane (wave-uniform
// SGPR operands for v_dot8) — zero LDS port pressure in the hot loop.
// G=2 batches amortize the register tile, barrier, and tail; each batch gated by
// its own T (uniform branch). Skeleton: ONE barrier/step, ping-pong planes,
// stale-S normalizer (exact), rbar bias correction — r13 numerics (absmax 16).
__global__ __launch_bounds__(512)
void k_fwd(const int* __restrict__ x, const int* __restrict__ Tl,
           const unsigned short* __restrict__ emTu,
           const float* __restrict__ P, const float* __restrict__ pric,
           const float* __restrict__ rscaleG, const float* __restrict__ rbarG,
           const unsigned short* __restrict__ tsumqG,
           const unsigned int* __restrict__ TQdw,
           float* __restrict__ out){
  extern __shared__ char smem[];
  unsigned char* aplB  = (unsigned char*)smem;           // [2 pp][2 g][256]
  unsigned int*  aplD  = (unsigned int*)smem;            // dword view [(pp*2+g)*64 + d]
  float*         statsF= (float*)(smem + 1024);          // [2 pp][64]: g*32 + {0-7 sig, 8-15 Sw, 16-23 Aq, 24-31 raw}
  int*           xls   = (int*)(smem + 1536);            // [2][512]

  const int t = threadIdx.x, blk = blockIdx.x, w = t>>6, L = t&63, j = t;
  const int b0 = 2*blk, b1 = 2*blk + 1;

  // ---- stage: Tr row into registers via SCALAR loads, then pin ----
  unsigned int trq[64];
  #pragma unroll
  for(int r=0;r<64;r++) trq[r] = TQdw[j*64 + r];
  #pragma unroll
  for(int r=0;r<64;r++) asm volatile("" : "+v"(trq[r]));

  xls[t]       = x[b0*HT + t];
  xls[512 + t] = x[b1*HT + t];
  const float rsc = rscaleG[j], rbr = rbarG[j];
#if ENC_BIASED
  unsigned short tsl[8];
  #pragma unroll
  for(int i=0;i<8;i++) tsl[i] = tsumqG[j*8 + i];
#endif
  const int Tb0 = Tl[b0], Tb1 = Tl[b1];
  const int Tmax = (Tb0 > Tb1)? Tb0 : Tb1;
  __syncthreads();

  // ---- init (t = 0), both batches ----
  float c0, c1;
  {
    int m0 = xls[0], m1 = xls[512];
    float Pv = P[j];
    float nv0 = bf2f((unsigned)emTu[(size_t)m0*HN + j]) * Pv;
    float nv1 = bf2f((unsigned)emTu[(size_t)m1*HN + j]) * Pv;
    float s0 = wsum(nv0), s1 = wsum(nv1);
    if(L==0){ statsF[0*64 + 0*32 + 24 + w] = s0; statsF[0*64 + 1*32 + 24 + w] = s1; }
    __syncthreads();
    float sV = statsF[L];
    float S0 = 0.f, S1 = 0.f;
    #pragma unroll
    for(int i=0;i<8;i++){ S0 += rdlanef(sV, 24+i); S1 += rdlanef(sV, 56+i); }
    float pr = pric[0];
    c0 = pr + __logf(S0);
    c1 = pr + __logf(S1);
    float nvd0 = nv0 * rcpf(S0), nvd1 = nv1 * rcpf(S1);
    // quantize both into plane 1 (read at tt=1)
    #pragma unroll
    for(int g=0; g<2; g++){
      float nvd = g ? nvd1 : nvd0;
      float Mw = fmaxf(wmax(nvd), 1e-30f);
      float sig = Mw * (1.0f/15.0f);
      int aq = __float2int_rn(nvd * (15.0f * rcpf(Mw)));
      float Sw = wsum(nvd);
#if ENC_BIASED
      float AqSw = wsum((float)aq);
#endif
      int aqn = __shfl_xor(aq, 1, 64);
      if((j&1)==0){
#if ENC_BIASED
        aplB[(1*2+g)*256 + (j>>1)] = (unsigned char)(((aq-8)&0xF) | (((aqn-8)&0xF)<<4));
#else
        aplB[(1*2+g)*256 + (j>>1)] = (unsigned char)((aq&0xF) | ((aqn&0xF)<<4));
#endif
      }
      if(L==0){
        statsF[64 + g*32 + w] = sig;
        statsF[64 + g*32 + 8 + w] = Sw;
#if ENC_BIASED
        statsF[64 + g*32 + 16 + w] = AqSw;
#endif
      }
    }
  }
  float eC0 = bf2f((unsigned)emTu[(size_t)xls[(Tb0>1)?1:0]*HN + j]);
  float eC1 = bf2f((unsigned)emTu[(size_t)xls[512 + ((Tb1>1)?1:0)]*HN + j]);

  for(int tt=1; tt<Tmax; tt++){
    __syncthreads();                      // the ONE barrier per step
    const int rb = (tt & 1), wb = rb ^ 1;
    float sV = statsF[rb*64 + L];
    int tn = (tt+1 < HT)? tt+1 : HT-1;

    #pragma unroll
    for(int g=0; g<2; g++){
      if(g ? (tt >= Tb1) : (tt >= Tb0)) continue;
      float eC = g ? eC1 : eC0;
      // prefetch next emission (issued early, hidden under the dots)
      float eN = bf2f((unsigned)emTu[(size_t)xls[g*512 + tn]*HN + j]);

      unsigned aV = aplD[(rb*2+g)*64 + L];
      int acc[8];
      #pragma unroll
      for(int i=0;i<8;i++) acc[i] = 0;
      #pragma unroll
      for(int c=0;c<16;c++){
        const int wi = c>>1;
        #pragma unroll
        for(int d=0;d<4;d++)
          acc[wi] = dot8q(trq[4*c+d], rdlaneu(aV, 4*c+d), acc[wi]);
      }

      float Sp = 0.f;
      #pragma unroll
      for(int i=0;i<8;i++) Sp += rdlanef(sV, g*32 + 8 + i);
      if(tt > 1){ if(g) c1 += __logf(Sp); else c0 += __logf(Sp); }
      float d_inv = rcpf(Sp);
      float abar  = Sp * (1.0f/512.0f);

      float Af = 0.f;
#if ENC_BIASED
      #pragma unroll
      for(int i=0;i<8;i++){
        float sg = rdlanef(sV, g*32 + i);
        float av = rdlanef(sV, g*32 + 16 + i);
        Af += sg * (float)(acc[i] + 8*((int)tsl[i] + (int)av) - 4096);
      }
#else
      #pragma unroll
      for(int i=0;i<8;i++) Af += rdlanef(sV, g*32 + i) * (float)acc[i];
#endif
      float D = rsc * Af + abar * rbr;
      float nvd = fmaxf(D * eC * d_inv, 0.0f);

      float Mw = fmaxf(wmax(nvd), 1e-30f);
      float sig = Mw * (1.0f/15.0f);
      int aq = __float2int_rn(nvd * (15.0f * rcpf(Mw)));
      float Sw = wsum(nvd);
#if ENC_BIASED
      float AqSw = wsum((float)aq);
#endif
      int aqn = __shfl_xor(aq, 1, 64);
      if((j&1)==0){
#if ENC_BIASED
        aplB[(wb*2+g)*256 + (j>>1)] = (unsigned char)(((aq-8)&0xF) | (((aqn-8)&0xF)<<4));
#else
        aplB[(wb*2+g)*256 + (j>>1)] = (unsigned char)((aq&0xF) | ((aqn&0xF)<<4));
#endif
      }
      if(L==0){
        statsF[wb*64 + g*32 + w] = sig;
        statsF[wb*64 + g*32 + 8 + w] = Sw;
#if ENC_BIASED
        statsF[wb*64 + g*32 + 16 + w] = AqSw;
#endif
      }
      if(g) eC1 = eN; else eC0 = eN;
    }
  }

  // ---- flush last step's S per batch ----
  __syncthreads();
  {
    const int f0 = Tb0 & 1, f1 = Tb1 & 1;
    float sV0 = statsF[f0*64 + L];
    float sV1 = statsF[f1*64 + L];
    float Sf0 = 0.f, Sf1 = 0.f;
    #pragma unroll
    for(int i=0;i<8;i++){
      Sf0 += rdlanef(sV0, 0*32 + 8 + i);
      Sf1 += rdlanef(sV1, 1*32 + 8 + i);
    }
    if(t==0){
      out[b0] = c0 + __logf(Sf0);
      out[b1] = c1 + __logf(Sf1);
    }
  }
}

extern "C" void kernel_launch(void* const* d_in, const int* in_sizes, int n_in,
                              void* d_out, int out_size, void* d_ws, size_t ws_size,
                              hipStream_t stream){
  const int*   x   = (const int*)d_in[0];
  const int*   T   = (const int*)d_in[1];
  const float* em  = (const float*)d_in[2];
  const float* tr  = (const float*)d_in[3];
  const float* pri = (const float*)d_in[4];
  float* out = (float*)d_out;

  char* ws = (char*)d_ws;
  float* em_lse = (float*)ws;                                   // 2 KiB
  float* P      = (float*)(ws + 2048);                          // 2 KiB
  float* pric   = (float*)(ws + 4096);                          // 16 B
  float* cmax   = (float*)(ws + 8192);                          // 2 KiB
  float* csum   = (float*)(ws + 10240);                         // 2 KiB
  float* rscale = (float*)(ws + 12288);                         // 2 KiB
  float* rbar   = (float*)(ws + 14336);                         // 2 KiB
  unsigned short* tsumq = (unsigned short*)(ws + 16384);        // 8 KiB
  unsigned short* emT = (unsigned short*)(ws + 24576);          // 4 MiB
  unsigned char*  TQ4 = (unsigned char*)(ws + 24576 + (size_t)HM*HN*2);  // 128 KiB

  k_em_lse<<<HN, 512, 0, stream>>>(em, em_lse);
  k_pri   <<<1,  512, 0, stream>>>(pri, P, pric);
  k_trcol <<<HN, 512, 0, stream>>>(tr, cmax, csum);
  k_trrow <<<HN, 512, 0, stream>>>(tr, cmax, csum, TQ4, rscale, rbar, tsumq);
  k_em_tab<<<dim3(HM/64, HN/64), 256, 0, stream>>>(em, em_lse, emT);

  const int lds_bytes = 5632;
  (void)hipFuncSetAttribute((const void*)k_fwd, hipFuncAttributeMaxDynamicSharedMemorySize, lds_bytes);
  k_fwd<<<HB/2, 512, lds_bytes, stream>>>(x, T, emT, P, pric, rscale, rbar, tsumq,
                                          (const unsigned int*)TQ4, out);
}

// Round 17
// 643.737 us; speedup vs baseline: 1.7097x; 1.7097x over previous
//
#include <hip/hip_runtime.h>
#include <math.h>

#define HN 512   // hidden states
#define HM 4096  // emission symbols
#define HB 64    // batch
#define HT 512   // max seq len

// ---- 4-bit dot path (encoding must match between prep + fwd) ----
#if __has_builtin(__builtin_amdgcn_udot8)
  #define ENC_BIASED 0
  __device__ __forceinline__ int dot8q(unsigned int a, unsigned int b, int c){
    return (int)__builtin_amdgcn_udot8(a, b, (unsigned int)c, false);
  }
#elif __has_builtin(__builtin_amdgcn_sdot8)
  #define ENC_BIASED 1
  __device__ __forceinline__ int dot8q(unsigned int a, unsigned int b, int c){
    return __builtin_amdgcn_sdot8((int)a, (int)b, c, false);
  }
#else
  #define ENC_BIASED 0
  __device__ __forceinline__ int dot4u8f(unsigned int a, unsigned int b, int c){
#if __has_builtin(__builtin_amdgcn_sdot4)
    return __builtin_amdgcn_sdot4((int)a, (int)b, c, false);
#else
    c += (int)(a & 0xffu)       * (int)(b & 0xffu);
    c += (int)((a>>8) & 0xffu)  * (int)((b>>8) & 0xffu);
    c += (int)((a>>16) & 0xffu) * (int)((b>>16) & 0xffu);
    c += (int)(a>>24)           * (int)(b>>24);
    return c;
#endif
  }
  __device__ __forceinline__ int dot8q(unsigned int a, unsigned int b, int c){
    unsigned int al = a & 0x0F0F0F0Fu, ah = (a>>4) & 0x0F0F0F0Fu;
    unsigned int bl = b & 0x0F0F0F0Fu, bh = (b>>4) & 0x0F0F0F0Fu;
    c = dot4u8f(al, bl, c);
    return dot4u8f(ah, bh, c);
  }
#endif

#if __has_builtin(__builtin_amdgcn_readlane)
  __device__ __forceinline__ unsigned rdlaneu(unsigned v, int l){
    return (unsigned)__builtin_amdgcn_readlane((int)v, l);
  }
  __device__ __forceinline__ float rdlanef(float v, int l){
    return __int_as_float(__builtin_amdgcn_readlane(__float_as_int(v), l));
  }
#else
  __device__ __forceinline__ unsigned rdlaneu(unsigned v, int l){ return (unsigned)__shfl((int)v, l, 64); }
  __device__ __forceinline__ float rdlanef(float v, int l){ return __shfl(v, l, 64); }
#endif

__device__ __forceinline__ float rcpf(float x){
#if __has_builtin(__builtin_amdgcn_rcpf)
  return __builtin_amdgcn_rcpf(x);
#else
  return 1.0f / x;
#endif
}

__device__ __forceinline__ float wsum(float v){
  #pragma unroll
  for(int o=32;o>0;o>>=1) v += __shfl_xor(v,o,64);
  return v;
}
__device__ __forceinline__ float wmax(float v){
  #pragma unroll
  for(int o=32;o>0;o>>=1) v = fmaxf(v,__shfl_xor(v,o,64));
  return v;
}

__device__ __forceinline__ float blockSum512(float v, float* red, float* bc){
  v = wsum(v);
  if((threadIdx.x & 63)==0) red[threadIdx.x>>6] = v;
  __syncthreads();
  if(threadIdx.x < 64){
    float s = (threadIdx.x<8)? red[threadIdx.x] : 0.0f;
    #pragma unroll
    for(int o=4;o>0;o>>=1) s += __shfl_xor(s,o,64);
    if(threadIdx.x==0) *bc = s;
  }
  __syncthreads();
  return *bc;
}
__device__ __forceinline__ float blockMax512(float v, float* red, float* bc){
  v = wmax(v);
  if((threadIdx.x & 63)==0) red[threadIdx.x>>6] = v;
  __syncthreads();
  if(threadIdx.x < 64){
    float s = (threadIdx.x<8)? red[threadIdx.x] : -INFINITY;
    #pragma unroll
    for(int o=4;o>0;o>>=1) s = fmaxf(s, __shfl_xor(s,o,64));
    if(threadIdx.x==0) *bc = s;
  }
  __syncthreads();
  return *bc;
}

__device__ __forceinline__ unsigned short f2bf(float f){
  unsigned int u = __float_as_uint(f);
  unsigned int r = (u + 0x7fffu + ((u>>16)&1u)) >> 16;  // RNE
  return (unsigned short)r;
}
__device__ __forceinline__ float bf2f(unsigned int w){ return __uint_as_float(w<<16); }

// ---------------- prep kernels ----------------

__global__ __launch_bounds__(512) void k_em_lse(const float* __restrict__ em, float* __restrict__ em_lse){
  __shared__ float red[8]; __shared__ float bc;
  int r = blockIdx.x;
  const float* row = em + (size_t)r*HM;
  float mx = -INFINITY;
  for(int i=threadIdx.x;i<HM;i+=512) mx = fmaxf(mx, row[i]);
  mx = blockMax512(mx, red, &bc);
  float s = 0.f;
  for(int i=threadIdx.x;i<HM;i+=512) s += expf(row[i]-mx);
  s = blockSum512(s, red, &bc);
  if(threadIdx.x==0) em_lse[r] = mx + logf(s);
}

__global__ __launch_bounds__(512) void k_pri(const float* __restrict__ pri, float* __restrict__ P, float* __restrict__ pric){
  __shared__ float red[8]; __shared__ float bc;
  int j = threadIdx.x;
  float v = pri[j];
  float mx = blockMax512(v, red, &bc);
  float w = expf(v-mx);
  float s = blockSum512(w, red, &bc);
  P[j] = w;
  if(j==0) *pric = -logf(s);
}

// emT[m][j] = bf16( exp(log_em[j][m]) ), LDS-tiled transpose
__global__ __launch_bounds__(256) void k_em_tab(const float* __restrict__ em, const float* __restrict__ em_lse,
                                                unsigned short* __restrict__ emT){
  __shared__ unsigned short tile[64][66];
  __shared__ float lsl[64];
  int m0 = blockIdx.x*64, j0 = blockIdx.y*64;
  int tx = threadIdx.x & 63, ty = threadIdx.x >> 6;
  if(threadIdx.x < 64) lsl[threadIdx.x] = em_lse[j0 + threadIdx.x];
  __syncthreads();
  #pragma unroll
  for(int r=0;r<16;r++){
    int jl = ty*16 + r;
    float v = em[(size_t)(j0+jl)*HM + m0 + tx];
    tile[jl][tx] = f2bf(expf(v - lsl[jl]));
  }
  __syncthreads();
  #pragma unroll
  for(int r=0;r<16;r++){
    int ml = ty*16 + r;
    emT[(size_t)(m0+ml)*HN + j0 + tx] = tile[tx][ml];
  }
}

// column stats of transition col-softmax
__global__ __launch_bounds__(512) void k_trcol(const float* __restrict__ tr,
                                               float* __restrict__ cmax, float* __restrict__ csum){
  __shared__ float red[8]; __shared__ float bc;
  int k = blockIdx.x, j = threadIdx.x;
  float v = tr[(size_t)j*HN + k];
  float mx = blockMax512(v, red, &bc);
  float s  = blockSum512(expf(v-mx), red, &bc);
  if(j==0){ cmax[k] = mx; csum[k] = s; }
}

// row pass: Tr[j,k] -> u4 q = round(Tr*15/rowmax). Byte at j*256 + (k>>5)*16 +
// ((k&31)>>1): lo = even k, hi = k+1 (matches alpha packing).
// rscale[j]=rm/15; rbar[j]=rowsum residual; tsumq[j][w] = per-64k-slice q sum.
__global__ __launch_bounds__(512) void k_trrow(const float* __restrict__ tr,
                                               const float* __restrict__ cmax, const float* __restrict__ csum,
                                               unsigned char* __restrict__ TQ4,
                                               float* __restrict__ rscale, float* __restrict__ rbar,
                                               unsigned short* __restrict__ tsumq){
  __shared__ float red[8]; __shared__ float bc;
  int j = blockIdx.x, k = threadIdx.x;
  float v = expf(tr[(size_t)j*HN + k] - cmax[k]) / csum[k];
  float rm = blockMax512(v, red, &bc);
  int q = __float2int_rn(v * (15.0f/rm));          // 0..15
  float rs = blockSum512(v, red, &bc);             // true row sum
  float qs = blockSum512((float)q, red, &bc);      // total q sum
  float wq = wsum((float)q);                       // per-64k-slice q sum
  int qn = __shfl_down(q, 1, 64);
  if((k & 1)==0){
#if ENC_BIASED
    unsigned char by = (unsigned char)(((q-8)&0xF) | (((qn-8)&0xF)<<4));
#else
    unsigned char by = (unsigned char)((q&0xF) | ((qn&0xF)<<4));
#endif
    TQ4[(size_t)j*256 + ((k>>5)<<4) + ((k&31)>>1)] = by;
  }
  if((k&63)==0) tsumq[j*8 + (k>>6)] = (unsigned short)(int)wq;
  if(k==0){
    rscale[j] = rm * (1.0f/15.0f);
    rbar[j]   = rs - (rm * (1.0f/15.0f)) * qs;
  }
}

// ---------------- forward recurrence ----------------
// 64 blocks (1/batch), 512 threads = 8 waves; thread = state j, full 512-k dot.
// Tr row (256 B u4 = 64 dwords) in REGISTERS: scalar dword fill + pin + the
// amdgpu_waves_per_eu(1,2) attribute. Cross-round evidence: r7 (attribute present,
// 64-dword array, 512 thr) -> VGPR 116 RESIDENT; r13/r15/r16 (no attribute, same
// fill) -> VGPR 36-52 spilled; r5 (attribute, 128-dword) -> exceeds the ~116 cap,
// spilled. 64 dwords + ~45 working fits the attribute-raised cap.
// alpha plane + stats: ONE ds_read_b32 lane-gather per wave + v_readlane
// (compile-time lane) -> wave-uniform SGPR operands for v_dot8. Hot loop issues
// ~2 LDS instructions per wave per step (the r11/r13/r14 LDS-port bound is gone).
// Skeleton: ONE barrier/step, ping-pong planes, stale-S normalizer (exact),
// rbar quantization-bias correction — absmax-16 numerics unchanged since r13.
__global__ __launch_bounds__(512) __attribute__((amdgpu_waves_per_eu(1, 2)))
void k_fwd(const int* __restrict__ x, const int* __restrict__ Tl,
           const unsigned short* __restrict__ emTu,
           const float* __restrict__ P, const float* __restrict__ pric,
           const float* __restrict__ rscaleG, const float* __restrict__ rbarG,
           const unsigned short* __restrict__ tsumqG,
           const unsigned int* __restrict__ TQdw,
           float* __restrict__ out){
  extern __shared__ char smem[];
  unsigned char* aplB  = (unsigned char*)smem;          // [2][256] alpha u4 planes
  unsigned int*  aplD  = (unsigned int*)smem;           // dword view [128]
  float*         statsF= (float*)(smem + 512);          // [2][32]: 0-7 sig, 8-15 Sw, 16-23 AqS, 24-31 raw
  int*           xls   = (int*)(smem + 768);            // 2048 B
  // total 2816 B

  const int t = threadIdx.x, b = blockIdx.x, w = t>>6, L = t&63, j = t;

  // ---- stage: Tr row into registers via SCALAR loads, then pin ----
  unsigned int trq[64];
  #pragma unroll
  for(int r=0;r<64;r++) trq[r] = TQdw[j*64 + r];
  #pragma unroll
  for(int r=0;r<64;r++) asm volatile("" : "+v"(trq[r]));

  xls[t] = x[b*HT + t];
  const float rsc = rscaleG[j], rbr = rbarG[j];
#if ENC_BIASED
  unsigned short tsl[8];
  #pragma unroll
  for(int i=0;i<8;i++) tsl[i] = tsumqG[j*8 + i];
#endif
  int Tb = Tl[b];
  __syncthreads();

  // ---- init (t = 0) ----
  int m = xls[0];
  float e0 = bf2f((unsigned)emTu[(size_t)m*HN + j]);
  float nvr = e0 * P[j];
  {
    float s = wsum(nvr);
    if(L==0) statsF[32 + 24 + w] = s;                 // raw S parts in buf1 spare
  }
  __syncthreads();
  float S0;
  {
    float sV = statsF[32 + (L&31)];
    S0 = 0.f;
    #pragma unroll
    for(int i=0;i<8;i++) S0 += rdlanef(sV, 24+i);
  }
  float c_acc = pric[0] + __logf(S0);
  float nvd = nvr * rcpf(S0);
  // quantize + stats into buffer 1 (read at tt=1)
  {
    float Mw = fmaxf(wmax(nvd), 1e-30f);
    float sig = Mw * (1.0f/15.0f);
    int aq = __float2int_rn(nvd * (15.0f * rcpf(Mw)));
    float Sw = wsum(nvd);
#if ENC_BIASED
    float AqSw = wsum((float)aq);
#endif
    int aqn = __shfl_xor(aq, 1, 64);
    if((j&1)==0){
#if ENC_BIASED
      aplB[256 + (j>>1)] = (unsigned char)(((aq-8)&0xF) | (((aqn-8)&0xF)<<4));
#else
      aplB[256 + (j>>1)] = (unsigned char)((aq&0xF) | ((aqn&0xF)<<4));
#endif
    }
    if(L==0){
      statsF[32 + w] = sig; statsF[32 + 8 + w] = Sw;
#if ENC_BIASED
      statsF[32 + 16 + w] = AqSw;
#endif
    }
  }
  int mn = xls[(Tb>1)?1:0];
  float eC = bf2f((unsigned)emTu[(size_t)mn*HN + j]);

  for(int tt=1; tt<Tb; tt++){
    __syncthreads();                      // the ONE barrier per step
    const int rb = (tt & 1), wb = rb ^ 1;

    // [gather] one b32 each: alpha dword L, stats dword (L&31)
    unsigned aV = aplD[rb*64 + L];
    float    sV = statsF[rb*32 + (L&31)];

    // [a] full-row dot: 64 v_dot8, alpha via readlane (SGPR operand)
    int acc[8];
    #pragma unroll
    for(int i=0;i<8;i++) acc[i] = 0;
    #pragma unroll
    for(int c=0;c<16;c++){
      const int wi = c>>1;
      #pragma unroll
      for(int d=0;d<4;d++)
        acc[wi] = dot8q(trq[4*c+d], rdlaneu(aV, 4*c+d), acc[wi]);
    }

    // [b] previous-step stats via readlane
    float Sp = 0.f;
    #pragma unroll
    for(int i=0;i<8;i++) Sp += rdlanef(sV, 8+i);
    if(tt > 1) c_acc += __logf(Sp);
    float d_inv = rcpf(Sp);
    float abar  = Sp * (1.0f/512.0f);

    float Af = 0.f;
#if ENC_BIASED
    #pragma unroll
    for(int i=0;i<8;i++){
      float sg = rdlanef(sV, i);
      float av = rdlanef(sV, 16+i);
      Af += sg * (float)(acc[i] + 8*((int)tsl[i] + (int)av) - 4096);
    }
#else
    #pragma unroll
    for(int i=0;i<8;i++) Af += rdlanef(sV, i) * (float)acc[i];
#endif
    float D = rsc * Af + abar * rbr;
    nvd = fmaxf(D * eC * d_inv, 0.0f);

    // prefetch next emission
    int tn = (tt+1 < HT)? tt+1 : HT-1;
    mn = xls[tn];
    float eN = bf2f((unsigned)emTu[(size_t)mn*HN + j]);

    // [e] wave-local finalize: quantize vs wave max, write plane wb
    float Mw = fmaxf(wmax(nvd), 1e-30f);
    float sig = Mw * (1.0f/15.0f);
    int aq = __float2int_rn(nvd * (15.0f * rcpf(Mw)));
    float Sw = wsum(nvd);
#if ENC_BIASED
    float AqSw = wsum((float)aq);
#endif
    int aqn = __shfl_xor(aq, 1, 64);
    if((j&1)==0){
#if ENC_BIASED
      aplB[256*wb + (j>>1)] = (unsigned char)(((aq-8)&0xF) | (((aqn-8)&0xF)<<4));
#else
      aplB[256*wb + (j>>1)] = (unsigned char)((aq&0xF) | ((aqn&0xF)<<4));
#endif
    }
    if(L==0){
      statsF[wb*32 + w] = sig; statsF[wb*32 + 8 + w] = Sw;
#if ENC_BIASED
      statsF[wb*32 + 16 + w] = AqSw;
#endif
    }
    eC = eN;
  }

  // ---- flush last step's S ----
  __syncthreads();
  {
    const int fb = (Tb & 1);
    float sV = statsF[fb*32 + (L&31)];
    float Sf = 0.f;
    #pragma unroll
    for(int i=0;i<8;i++) Sf += rdlanef(sV, 8+i);
    if(t==0) out[b] = c_acc + __logf(Sf);
  }
}

extern "C" void kernel_launch(void* const* d_in, const int* in_sizes, int n_in,
                              void* d_out, int out_size, void* d_ws, size_t ws_size,
                              hipStream_t stream){
  const int*   x   = (const int*)d_in[0];
  const int*   T   = (const int*)d_in[1];
  const float* em  = (const float*)d_in[2];
  const float* tr  = (const float*)d_in[3];
  const float* pri = (const float*)d_in[4];
  float* out = (float*)d_out;

  char* ws = (char*)d_ws;
  float* em_lse = (float*)ws;                                   // 2 KiB
  float* P      = (float*)(ws + 2048);                          // 2 KiB
  float* pric   = (float*)(ws + 4096);                          // 16 B
  float* cmax   = (float*)(ws + 8192);                          // 2 KiB
  float* csum   = (float*)(ws + 10240);                         // 2 KiB
  float* rscale = (float*)(ws + 12288);                         // 2 KiB
  float* rbar   = (float*)(ws + 14336);                         // 2 KiB
  unsigned short* tsumq = (unsigned short*)(ws + 16384);        // 8 KiB
  unsigned short* emT = (unsigned short*)(ws + 24576);          // 4 MiB
  unsigned char*  TQ4 = (unsigned char*)(ws + 24576 + (size_t)HM*HN*2);  // 128 KiB

  k_em_lse<<<HN, 512, 0, stream>>>(em, em_lse);
  k_pri   <<<1,  512, 0, stream>>>(pri, P, pric);
  k_trcol <<<HN, 512, 0, stream>>>(tr, cmax, csum);
  k_trrow <<<HN, 512, 0, stream>>>(tr, cmax, csum, TQ4, rscale, rbar, tsumq);
  k_em_tab<<<dim3(HM/64, HN/64), 256, 0, stream>>>(em, em_lse, emT);

  const int lds_bytes = 2816;
  (void)hipFuncSetAttribute((const void*)k_fwd, hipFuncAttributeMaxDynamicSharedMemorySize, lds_bytes);
  k_fwd<<<HB, 512, lds_bytes, stream>>>(x, T, emT, P, pric, rscale, rbar, tsumq,
                                        (const unsigned int*)TQ4, out);
}